// Round 11
// baseline (1851.689 us; speedup 1.0000x reference)
//
#include <hip/hip_runtime.h>

// Attractor net (all I/O float32): c = x@Win^T + bin; a=0; 15x: a = tanh(a@Ws^T + b + c),
// Ws = 0.5(W+W^T); y = a@Wout^T + bout.  x (65536,256), N=512, C=256.
//
// Round-12: counter-phase pipelining on the r11 int8 structure. r11 diagnosis: kernel is
// PHASE-ALTERNATING (barrier-synced MFMA loop then epilogue; MfmaUtil 21.7 + VALUBusy 39
// ~ sum of exclusive phases; no pipe saturated). Fix: split the 64 samples into two
// independent sets A/B (32 each, 16KB LDS buffers at 0 / 16384); each phase interleaves
// set-X's 16-step i8 MFMA pass with set-Y's 32-value tanh+quant epilogue in one
// instruction stream -> epilogue VALU executes in the MFMA pipe's shadow (m114 co-issue).
//  - 29 phases, 1 barrier each: P0 A-MFMA; then 27x [X-MFMA || Y-epi]; drain B-epi.
//  - Each phase reads one buffer, writes the other: in-place, no dbuf needed.
//  - Ws A-fragments shared by both sets (same wave = same feature rows); depth-1
//    ping-pong chain continuous across all 28 MFMA passes (s=15 wraps to next pass s=0).
//  - Cost: Ws swept 28x/block (was 14); stagger kept to spread L2. +15 barriers.
//  - Registers ~ zE 32 + acc 32 + c_pk 32 + Ab 16 + temps <= 128 (proven budget);
//    spill (WRITE_SIZE > 300MB) is the declared failure signature.
// Epilogue math unchanged from r11 (c2 prescale + magic-fma quant, bit-identical).

using bf16x8 = __attribute__((ext_vector_type(8))) __bf16;
using f32x16 = __attribute__((ext_vector_type(16))) float;
using i32x4  = __attribute__((ext_vector_type(4))) int;
using i32x16 = __attribute__((ext_vector_type(16))) int;

// round-to-nearest bf16 pack of two floats into one u32 (lo = a, hi = b)
__device__ __forceinline__ unsigned int pack2bf(float a, float b) {
  unsigned int ua = __builtin_bit_cast(unsigned int, a);
  unsigned int ub = __builtin_bit_cast(unsigned int, b);
  return ((ua + 0x8000u) >> 16) | ((ub + 0x8000u) & 0xffff0000u);
}

__device__ __forceinline__ unsigned short f2bf(float v) {
  unsigned int u = __builtin_bit_cast(unsigned int, v);
  return (unsigned short)((u + 0x7fffu + ((u >> 16) & 1u)) >> 16);  // RNE
}

__device__ __forceinline__ float fast_tanh(float x) {
  float e = __builtin_amdgcn_exp2f(x * 2.885390082f);
  float r = __builtin_amdgcn_rcpf(e + 1.0f);
  return __builtin_fmaf(-2.0f, r, 1.0f);
}

__device__ __forceinline__ f32x16 mfma_bf(uint4 a, uint4 b, f32x16 c) {
  return __builtin_amdgcn_mfma_f32_32x32x16_bf16(
      __builtin_bit_cast(bf16x8, a), __builtin_bit_cast(bf16x8, b), c, 0, 0, 0);
}

__device__ __forceinline__ i32x16 mfma_i8(uint4 a, uint4 b, i32x16 c) {
  return __builtin_amdgcn_mfma_i32_32x32x32_i8(
      __builtin_bit_cast(i32x4, a), __builtin_bit_cast(i32x4, b), c, 0, 0, 0);
}

// quantize 4 tanh outputs (in (-1,1)) to i8 at scale 1/127, pack to u32
__device__ __forceinline__ unsigned int q8pack(float t0, float t1, float t2, float t3) {
  int q0 = (int)__builtin_rintf(t0 * 127.f);
  int q1 = (int)__builtin_rintf(t1 * 127.f);
  int q2 = (int)__builtin_rintf(t2 * 127.f);
  int q3 = (int)__builtin_rintf(t3 * 127.f);
  return (q0 & 255) | ((q1 & 255) << 8) | ((q2 & 255) << 16) | ((unsigned)q3 << 24);
}

// ---------------- prep ---------------- (identical to r10/r11)
__global__ void prep(const float* __restrict__ W,
                     const float* __restrict__ Win,
                     const float* __restrict__ Wout,
                     signed char* __restrict__ WsI8,
                     signed char* __restrict__ WoutRI8,
                     unsigned short* __restrict__ WinBf) {
  int t = blockIdx.x * 256 + threadIdx.x;   // 0 .. 524287
  if (t < 262144) {
    int j = t & 15, L = (t >> 4) & 63, mtG = (t >> 10) & 15, s = (t >> 14) & 15;
    int m = mtG * 32 + (L & 31);
    int k = s * 32 + (L >> 5) * 16 + j;
    float v = __builtin_rintf(0.5f * (W[m * 512 + k] + W[k * 512 + m]) * 2048.f);
    v = fminf(127.f, fmaxf(-127.f, v));
    WsI8[t] = (signed char)(int)v;
  } else if (t < 393216) {
    WinBf[t - 262144] = f2bf(Win[t - 262144]);
  } else {
    int u = t - 393216;
    int j = u & 15, L = (u >> 4) & 63, wv = (u >> 10) & 7, s = (u >> 13) & 15;
    int m = wv * 32 + (L & 31);
    int k = s * 32 + (L >> 5) * 16 + j;
    float r = Wout[m * 512 + k] - ((m == k) ? 1.f : 0.f);
    r = fminf(127.f, fmaxf(-127.f, __builtin_rintf(r * 2048.f)));
    WoutRI8[u] = (signed char)(int)r;
  }
}

// ---------------- main fused kernel ----------------
__global__ __launch_bounds__(512, 4) void attractor_kernel(
    const float* __restrict__ x,              // 65536 x 256 f32
    const unsigned short* __restrict__ WinBf, // 512 x 256 bf16
    const float* __restrict__ binf,           // 512 f32
    const float* __restrict__ brecf,          // 512 f32
    const signed char* __restrict__ WoutRI8,  // 128 KB i8 fragments
    const float* __restrict__ boutf,          // 256 f32
    const signed char* __restrict__ WsI8,     // 256 KB i8 fragments
    float* __restrict__ y)                    // 65536 x 256 f32
{
  __shared__ uint4 smem4[4160];               // 66,560 B: a_A 16KB @0, a_B 16KB @16384;
  char* aC = (char*)smem4;                    // y-stage overlay 64x65 uint4

  const int tid  = threadIdx.x;
  const int lane = tid & 63;
  const int w    = tid >> 6;    // wave 0..7
  const int il   = lane & 31;   // row-within-32-tile; 5-bit LDS swizzle key
  const int g    = lane >> 5;   // k-group (0/1)
  const int sw   = w * 2;       // per-wave K-sweep stagger
  const int blk  = blockIdx.x;

  const float4* __restrict__ xf4  = (const float4*)x;       // row = 64 float4
  const uint4* __restrict__ Win4  = (const uint4*)WinBf;    // row = 32 uint4
  uint4* __restrict__ y4 = (uint4*)y;                       // row = 64 uint4

  unsigned int c_pk[2][2][8];   // [mt][set][8]: c2 = 2.885390082*c, bf16-packed

  // i8-a store of the 4-value word (mt,p) for set-base sb (row = il, 32 16B-units/row)
  auto storeA = [&](int sb, int mt, int p, unsigned int pk) {
    const int u = w * 4 + mt * 2 + (p >> 1);
    *(unsigned int*)(aC + sb + il * 512 + ((u ^ il) << 4) + 8 * (p & 1) + 4 * g) = pk;
  };

  // ---------- Phase 1: in_proj  c^T = Win @ x^T  (bf16, K = 256 -> 16 steps) ----------
  {
    f32x16 accf[2][2];
    #pragma unroll
    for (int mt = 0; mt < 2; ++mt)
      #pragma unroll
      for (int ss = 0; ss < 2; ++ss)
        #pragma unroll
        for (int r = 0; r < 16; ++r) accf[mt][ss][r] = 0.0f;

    #pragma unroll 2
    for (int s = 0; s < 16; ++s) {
      uint4 A[2], B[2];
      #pragma unroll
      for (int mt = 0; mt < 2; ++mt) {
        int m = w * 64 + mt * 32 + il;
        A[mt] = Win4[m * 32 + 2 * s + g];
      }
      #pragma unroll
      for (int ss = 0; ss < 2; ++ss) {
        int i = blk * 64 + ss * 32 + il;
        float4 f0 = xf4[i * 64 + 4 * s + 2 * g + 0];
        float4 f1 = xf4[i * 64 + 4 * s + 2 * g + 1];
        B[ss].x = pack2bf(f0.x, f0.y);
        B[ss].y = pack2bf(f0.z, f0.w);
        B[ss].z = pack2bf(f1.x, f1.y);
        B[ss].w = pack2bf(f1.z, f1.w);
      }
      #pragma unroll
      for (int mt = 0; mt < 2; ++mt)
        #pragma unroll
        for (int ss = 0; ss < 2; ++ss)
          accf[mt][ss] = mfma_bf(A[mt], B[ss], accf[mt][ss]);
    }

    // fold biases; stash c2 = 2.885390082*c (bf16); a1 = tanh(c) -> both set buffers
    #pragma unroll
    for (int mt = 0; mt < 2; ++mt) {
      #pragma unroll
      for (int p = 0; p < 4; ++p) {
        const int n0 = w * 64 + mt * 32 + 8 * p + 4 * g;
        float b0 = binf[n0 + 0] + brecf[n0 + 0];
        float b1 = binf[n0 + 1] + brecf[n0 + 1];
        float b2 = binf[n0 + 2] + brecf[n0 + 2];
        float b3 = binf[n0 + 3] + brecf[n0 + 3];
        #pragma unroll
        for (int ss = 0; ss < 2; ++ss) {
          float v0 = accf[mt][ss][4 * p + 0] + b0;
          float v1 = accf[mt][ss][4 * p + 1] + b1;
          float v2 = accf[mt][ss][4 * p + 2] + b2;
          float v3 = accf[mt][ss][4 * p + 3] + b3;
          c_pk[mt][ss][2 * p + 0] = pack2bf(2.885390082f * v0, 2.885390082f * v1);
          c_pk[mt][ss][2 * p + 1] = pack2bf(2.885390082f * v2, 2.885390082f * v3);
          storeA(ss * 16384, mt, p, q8pack(fast_tanh(v0), fast_tanh(v1),
                                           fast_tanh(v2), fast_tanh(v3)));
        }
      }
    }
  }

  // cross-barrier prefetch of first Ws fragments (se = sw)
  const uint4* Ws4 = (const uint4*)WsI8;      // frag (s,mtG) at uint4 idx (s*16+mtG)*64
  const uint4* pA = Ws4 + (2 * w) * 64 + lane;
  uint4 Ab[2][2];   // [slot][mt]
  Ab[0][0] = pA[sw * 1024];
  Ab[0][1] = pA[sw * 1024 + 64];

  __syncthreads();

  // ---------- Phase 2: 14 iterations per set, counter-phased ----------
  const float SE = 2.885390082f / 260096.f;   // 2*log2(e) * (1/(127*2048))
  const float QM = 12583039.0f;               // 2^23 + 2^22 + 127
  const int rdBase = il * 512;

  i32x16 zA[2], zB[2];

  // MFMA-only pass (prologue): accM = Ws @ a[sbR]
  auto phaseM = [&](i32x16 (&accM)[2], int sbR) {
    #pragma unroll
    for (int r = 0; r < 16; ++r) { accM[0][r] = 0; accM[1][r] = 0; }
    #pragma unroll 2
    for (int s = 0; s < 16; ++s) {
      const int se = (s + sw) & 15;
      const int sn = (s + 1 + sw) & 15;
      uint4 An0 = pA[sn * 1024];
      uint4 An1 = pA[sn * 1024 + 64];
      uint4 B = *(const uint4*)(aC + sbR + rdBase + (((2 * se + g) ^ il) << 4));
      accM[0] = mfma_i8(Ab[s & 1][0], B, accM[0]);
      accM[1] = mfma_i8(Ab[s & 1][1], B, accM[1]);
      Ab[(s + 1) & 1][0] = An0;
      Ab[(s + 1) & 1][1] = An1;
    }
  };

  // interleaved phase: accM = Ws @ a[sbR]  ||  epilogue of zE -> a[sbW] (set setE)
  auto phaseFull = [&](i32x16 (&accM)[2], int sbR,
                       i32x16 (&zE)[2], int setE, int sbW) {
    #pragma unroll
    for (int r = 0; r < 16; ++r) { accM[0][r] = 0; accM[1][r] = 0; }
    unsigned carry = 0;
    #pragma unroll
    for (int s = 0; s < 16; ++s) {
      // --- MFMA step (reads other set's buffer) ---
      const int se = (s + sw) & 15;
      const int sn = (s + 1 + sw) & 15;
      uint4 An0 = pA[sn * 1024];
      uint4 An1 = pA[sn * 1024 + 64];
      uint4 B = *(const uint4*)(aC + sbR + rdBase + (((2 * se + g) ^ il) << 4));
      accM[0] = mfma_i8(Ab[s & 1][0], B, accM[0]);
      accM[1] = mfma_i8(Ab[s & 1][1], B, accM[1]);
      Ab[(s + 1) & 1][0] = An0;
      Ab[(s + 1) & 1][1] = An1;
      // --- epilogue pair (independent of the MFMA: VALU rides the MAI shadow) ---
      const int mt_e = s >> 3, j = s & 7, p = j >> 1, h = j & 1;
      unsigned cw = c_pk[mt_e][setE][j];
      float c0 = __builtin_bit_cast(float, cw << 16);
      float c1 = __builtin_bit_cast(float, cw & 0xffff0000u);
      float e0 = __builtin_amdgcn_exp2f(
          __builtin_fmaf((float)zE[mt_e][4 * p + 2 * h + 0], SE, c0));
      float e1 = __builtin_amdgcn_exp2f(
          __builtin_fmaf((float)zE[mt_e][4 * p + 2 * h + 1], SE, c1));
      float r0 = __builtin_amdgcn_rcpf(e0 + 1.0f);
      float r1 = __builtin_amdgcn_rcpf(e1 + 1.0f);
      unsigned f0 = __builtin_bit_cast(unsigned, __builtin_fmaf(-254.f, r0, QM));
      unsigned f1 = __builtin_bit_cast(unsigned, __builtin_fmaf(-254.f, r1, QM));
      unsigned two = (f0 & 0xffu) | ((f1 & 0xffu) << 8);
      if (h == 0) {
        carry = two;
      } else {
        storeA(sbW, mt_e, p, carry | (two << 16));
      }
    }
  };

  // epilogue-only pass (drain)
  auto epiOnly = [&](i32x16 (&zE)[2], int setE, int sbW) {
    #pragma unroll
    for (int mt = 0; mt < 2; ++mt)
      #pragma unroll
      for (int p = 0; p < 4; ++p) {
        unsigned u01 = c_pk[mt][setE][2 * p + 0];
        unsigned u23 = c_pk[mt][setE][2 * p + 1];
        float c0 = __builtin_bit_cast(float, u01 << 16);
        float c1 = __builtin_bit_cast(float, u01 & 0xffff0000u);
        float c2 = __builtin_bit_cast(float, u23 << 16);
        float c3 = __builtin_bit_cast(float, u23 & 0xffff0000u);
        float e0 = __builtin_amdgcn_exp2f(__builtin_fmaf((float)zE[mt][4 * p + 0], SE, c0));
        float e1 = __builtin_amdgcn_exp2f(__builtin_fmaf((float)zE[mt][4 * p + 1], SE, c1));
        float e2 = __builtin_amdgcn_exp2f(__builtin_fmaf((float)zE[mt][4 * p + 2], SE, c2));
        float e3 = __builtin_amdgcn_exp2f(__builtin_fmaf((float)zE[mt][4 * p + 3], SE, c3));
        float r0 = __builtin_amdgcn_rcpf(e0 + 1.0f);
        float r1 = __builtin_amdgcn_rcpf(e1 + 1.0f);
        float r2 = __builtin_amdgcn_rcpf(e2 + 1.0f);
        float r3 = __builtin_amdgcn_rcpf(e3 + 1.0f);
        unsigned f0 = __builtin_bit_cast(unsigned, __builtin_fmaf(-254.f, r0, QM));
        unsigned f1 = __builtin_bit_cast(unsigned, __builtin_fmaf(-254.f, r1, QM));
        unsigned f2 = __builtin_bit_cast(unsigned, __builtin_fmaf(-254.f, r2, QM));
        unsigned f3 = __builtin_bit_cast(unsigned, __builtin_fmaf(-254.f, r3, QM));
        storeA(sbW, mt, p, (f0 & 0xffu) | ((f1 & 0xffu) << 8) |
                           ((f2 & 0xffu) << 16) | (f3 << 24));
      }
  };

  // schedule: P0 A-MFMA; 27x interleaved; drain B-epi. 1 barrier/phase.
  phaseM(zA, 0);                      // z_A(iter1) from a_A1
  __syncthreads();
  #pragma unroll 1
  for (int k = 1; k <= 14; ++k) {
    phaseFull(zB, 16384, zA, 0, 0);   // B-MFMA(k) || A-epi -> a_A(k+1)
    __syncthreads();
    if (k < 14) {
      phaseFull(zA, 0, zB, 1, 16384); // A-MFMA(k+1) || B-epi -> a_B(k+1)
      __syncthreads();
    }
  }
  epiOnly(zB, 1, 16384);              // a_B15
  __syncthreads();

  // ---------- Phase 3: out_proj  y^T = ([I|0]+R) @ a^T  (i8 R + identity column) ----------
  const float S = 1.f / 260096.f;
  const uint4* Wr4 = (const uint4*)WoutRI8;   // frag (s,w) at uint4 idx (s*8+w)*64
  const uint4* pR = Wr4 + w * 64 + lane;
  i32x16 o[2];
  #pragma unroll
  for (int ss = 0; ss < 2; ++ss)
    #pragma unroll
    for (int r = 0; r < 16; ++r) o[ss][r] = 0;

  #pragma unroll 2
  for (int s = 0; s < 16; ++s) {
    const int se = (s + sw) & 15;
    uint4 A = pR[se * 512];
    const int bu = rdBase + (((2 * se + g) ^ il) << 4);
    uint4 B0 = *(const uint4*)(aC + bu);
    uint4 B1 = *(const uint4*)(aC + bu + 16384);
    o[0] = mfma_i8(A, B0, o[0]);
    o[1] = mfma_i8(A, B1, o[1]);
  }

  // identity column + scale + bias (reads a buffers -> must precede the barrier)
  #pragma unroll
  for (int ss = 0; ss < 2; ++ss) {
    const int rowb = ss * 16384 + il * 512;
    uint4 Q0 = *(const uint4*)(aC + rowb + (((2 * w + 0) ^ il) << 4));
    uint4 Q1 = *(const uint4*)(aC + rowb + (((2 * w + 1) ^ il) << 4));
    #pragma unroll
    for (int p = 0; p < 4; ++p) {
      const int c0i = w * 32 + 8 * p + 4 * g;
      float4 bo = *(const float4*)(boutf + c0i);
      unsigned lo, hi;
      if      (p == 0) { lo = Q0.x; hi = Q0.y; }
      else if (p == 1) { lo = Q0.z; hi = Q0.w; }
      else if (p == 2) { lo = Q1.x; hi = Q1.y; }
      else             { lo = Q1.z; hi = Q1.w; }
      const unsigned wrd = g ? hi : lo;
      #pragma unroll
      for (int q = 0; q < 4; ++q) {
        int aq = (int)(signed char)(wrd >> (8 * q));
        float bq = (q == 0) ? bo.x : (q == 1) ? bo.y : (q == 2) ? bo.z : bo.w;
        float yv = __builtin_fmaf((float)o[ss][4 * p + q], S,
                   __builtin_fmaf((float)aq, 1.f / 127.f, bq));
        o[ss][4 * p + q] = __builtin_bit_cast(int, yv);
      }
    }
  }
  __syncthreads();   // done reading a; reuse LDS as y staging

  // stage f32 rows into LDS (stride-65 uint4 rows)
  uint4* yst4 = smem4;
  #pragma unroll
  for (int p = 0; p < 4; ++p) {
    const int c0 = w * 32 + 8 * p + 4 * g;
    #pragma unroll
    for (int ss = 0; ss < 2; ++ss) {
      const int irow = ss * 32 + il;
      uint4 r;
      r.x = (unsigned)o[ss][4 * p + 0];
      r.y = (unsigned)o[ss][4 * p + 1];
      r.z = (unsigned)o[ss][4 * p + 2];
      r.w = (unsigned)o[ss][4 * p + 3];
      yst4[irow * 65 + (c0 >> 2)] = r;
    }
  }
  __syncthreads();

  // coalesced f32 store: 4096 uint4 per block, 8 passes x 512 threads
  #pragma unroll
  for (int p = 0; p < 8; ++p) {
    int idx = p * 512 + tid;
    int row = idx >> 6;
    int col = idx & 63;
    y4[(blk * 64 + row) * 64 + col] = yst4[row * 65 + col];
  }
}

extern "C" void kernel_launch(void* const* d_in, const int* in_sizes, int n_in,
                              void* d_out, int out_size, void* d_ws, size_t ws_size,
                              hipStream_t stream) {
  const float* x    = (const float*)d_in[0];
  const float* Win  = (const float*)d_in[1];
  const float* bin  = (const float*)d_in[2];
  const float* W    = (const float*)d_in[3];
  const float* brec = (const float*)d_in[4];
  const float* Wout = (const float*)d_in[5];
  const float* bout = (const float*)d_in[6];

  signed char* WsI8       = (signed char*)d_ws;               // 262144 B
  signed char* WoutRI8    = WsI8 + 262144;                    // 131072 B
  unsigned short* WinBf   = (unsigned short*)(WsI8 + 393216); // 131072 bf16

  prep<<<2048, 256, 0, stream>>>(W, Win, Wout, WsI8, WoutRI8, WinBf);
  attractor_kernel<<<1024, 512, 0, stream>>>(x, WinBf, bin, brec, WoutRI8, bout,
                                             WsI8, (float*)d_out);
}